// Round 2
// baseline (3716.822 us; speedup 1.0000x reference)
//
#include <hip/hip_runtime.h>

// LSTMencoder: 2-layer biLSTM, B=256, T=2048, H=32 (4H=128 gates), F=32/64.
// One wave per (batch, dir) chain, persistent over T. All weights in VGPRs
// (straight-line code, no lambdas -> no scratch). Lanes 0..31 own gate rows
// (i_u, g_u), lanes 32..63 own (f_u, o_u) and the c/h state; one ds_bpermute
// per step moves P = sig(i)*tanh(g) across; h broadcast via 32 readlanes.
// Next-step input dot (float4 -> v_pk_fma) fills the bpermute latency window.

#define T_LEN 2048
#define BATCH 256

__device__ __forceinline__ float frcp(float x) { return __builtin_amdgcn_rcpf(x); }
__device__ __forceinline__ float rdlane(float v, int k) {
    return __int_as_float(__builtin_amdgcn_readlane(__float_as_int(v), k));
}

// issue prefetch loads into buffer PL, advance wave-uniform pointers (clamped)
#define LOADX(PL) do {                                                          \
    if (LAYER == 0) {                                                           \
        const float4* _o = reinterpret_cast<const float4*>(pOS);                \
        const float4* _s = reinterpret_cast<const float4*>(pIS);                \
        _Pragma("unroll") for (int _i = 0; _i < 4; ++_i) Xb[PL][_i] = _o[_i];   \
        _Pragma("unroll") for (int _i = 0; _i < F4-4; ++_i) Xb[PL][4+_i] = _s[_i];\
        if (np < T_LEN-1) { pOS += osStep; pIS += isStep; ++np; }               \
    } else {                                                                    \
        const float4* _h = reinterpret_cast<const float4*>(pH1);                \
        _Pragma("unroll") for (int _i = 0; _i < F4; ++_i) Xb[PL][_i] = _h[_i];  \
        if (np < T_LEN-1) { pH1 += hStep; ++np; }                               \
    } } while (0)

// input-side pre-activation for the NEXT step from buffer PD (pk_fma)
#define DOT(PD) do {                                                            \
    float4 _a4 = make_float4(0.f,0.f,0.f,0.f), _b4 = make_float4(0.f,0.f,0.f,0.f);\
    _Pragma("unroll") for (int _i = 0; _i < F4; ++_i) {                         \
        _a4 += Xb[PD][_i] * wA4[_i];                                            \
        _b4 += Xb[PD][_i] * wB4[_i];                                            \
    }                                                                           \
    inA = biasA + ((_a4.x + _a4.y) + (_a4.z + _a4.w));                          \
    inB = biasB + ((_b4.x + _b4.y) + (_b4.z + _b4.w));                          \
    } while (0)

#define STEP(PL, PD) do {                                                       \
    LOADX(PL);                              /* max in-flight distance */        \
    float accA = inA, accB = inB;                                               \
    _Pragma("unroll") for (int _k = 0; _k < 32; ++_k) {                         \
        accA = fmaf(hs[_k], uA[_k], accA);                                      \
        accB = fmaf(hs[_k], uB[_k], accB);                                      \
    }                                                                           \
    float sA = frcp(1.f + __expf(-accA));   /* sig(i) | sig(f) */               \
    float rB = frcp(1.f + __expf(accB * mB));                                   \
    float sB = fmaf(sBa, rB, sBb);          /* tanh(g) | sig(o) */              \
    float Pv = sA * sB;                                                         \
    int Pri = __builtin_amdgcn_ds_bpermute(bpa, __float_as_int(Pv));            \
    DOT(PD);                                /* fills bpermute window */         \
    c = fmaf(sA, c, __int_as_float(Pri));   /* upper: sig(f)*c + P  */          \
    float tc = fmaf(2.f, frcp(1.f + __expf(-2.f * c)), -1.f);                   \
    float hj = sB * tc;                     /* upper: sig(o)*tanh(c) */         \
    if (up) *pSt = hj;                                                          \
    pSt += stStep;                                                              \
    _Pragma("unroll") for (int _k = 0; _k < 32; ++_k) hs[_k] = rdlane(hj, 32+_k);\
    } while (0)

template<int LAYER>
__global__ __launch_bounds__(64, 1) void lstm_rec(
        const float* __restrict__ OS, const float* __restrict__ IS,
        const float* __restrict__ Wih, const float* __restrict__ Whh,
        const float* __restrict__ bih, const float* __restrict__ bhh,
        const float* __restrict__ h1in, float* __restrict__ outp)
{
    constexpr int F    = (LAYER == 0) ? 32 : 64;
    constexpr int F4   = F / 4;
    constexpr int NBUF = (LAYER == 0) ? 4 : 2;   // prefetch depth

    const int l   = threadIdx.x;     // 0..63
    const int b   = blockIdx.x;      // 0..255
    const int dir = blockIdx.y;      // 0 fwd, 1 bwd
    const int gA  = l;               // row: i_u (l<32) | f_u (l>=32)
    const int gB  = 64 + l;          // row: g_u (l<32) | o_u (l>=32)
    const int u   = l & 31;
    const bool up = (l >= 32);

    // ---- per-lane weights, register-resident ----
    float4 wA4[F4], wB4[F4];
    const float4* pwA = reinterpret_cast<const float4*>(Wih + ((size_t)dir*128 + gA)*F);
    const float4* pwB = reinterpret_cast<const float4*>(Wih + ((size_t)dir*128 + gB)*F);
#pragma unroll
    for (int i = 0; i < F4; ++i) { wA4[i] = pwA[i]; wB4[i] = pwB[i]; }
    float uA[32], uB[32];
    const float4* puA = reinterpret_cast<const float4*>(Whh + ((size_t)dir*128 + gA)*32);
    const float4* puB = reinterpret_cast<const float4*>(Whh + ((size_t)dir*128 + gB)*32);
#pragma unroll
    for (int i = 0; i < 8; ++i) {
        float4 a = puA[i], bb = puB[i];
        uA[4*i+0]=a.x;  uA[4*i+1]=a.y;  uA[4*i+2]=a.z;  uA[4*i+3]=a.w;
        uB[4*i+0]=bb.x; uB[4*i+1]=bb.y; uB[4*i+2]=bb.z; uB[4*i+3]=bb.w;
    }
    const float biasA = bih[dir*128+gA] + bhh[dir*128+gA];
    const float biasB = bih[dir*128+gB] + bhh[dir*128+gB];

    // ---- wave-uniform stream pointers ----
    const int te0 = dir ? (T_LEN-1) : 0;
    const float* pOS = nullptr; const float* pIS = nullptr; const float* pH1 = nullptr;
    ptrdiff_t osStep = 0, isStep = 0, hStep = 0, stStep = 0;
    float* pSt;
    if (LAYER == 0) {
        pOS = OS + ((size_t)b*T_LEN + te0)*16;
        pIS = IS + ((size_t)b*T_LEN + (T_LEN-1 - te0))*16;
        osStep = dir ? -16 : 16; isStep = -osStep;
        pSt = outp + (size_t)te0*(BATCH*64) + b*64 + dir*32 + u;   // h1[te][b][.]
        stStep = dir ? -(BATCH*64) : (BATCH*64);
    } else {
        pH1 = h1in + ((size_t)te0*BATCH + b)*64;
        hStep = dir ? -(BATCH*64) : (BATCH*64);
        pSt = outp + ((size_t)b*T_LEN + te0)*64 + dir*32 + u;      // out[b][te][.]
        stStep = dir ? -64 : 64;
    }

    const int   bpa = (l ^ 32) << 2;          // bpermute byte address
    const float mB  = up ? -1.f : -2.f;       // gate-B exp argument multiplier
    const float sBa = up ?  1.f :  2.f;       // sB = sBa*rB + sBb
    const float sBb = up ?  0.f : -1.f;

    float hs[32];
#pragma unroll
    for (int k = 0; k < 32; ++k) hs[k] = 0.f;
    float c = 0.f;
    float inA, inB;
    int np = 0;                               // advances issued (clamp at T-1)

    float4 Xb[NBUF][F4];

    // prologue: fill pipeline, preact for step 0
    LOADX(0); LOADX(1);
    if constexpr (NBUF == 4) { LOADX(2); LOADX(3); }
    DOT(0);

#pragma unroll 1
    for (int tt = 0; tt < T_LEN; tt += NBUF) {
        if constexpr (NBUF == 4) {
            STEP(0,1); STEP(1,2); STEP(2,3); STEP(3,0);
        } else {
            STEP(0,1); STEP(1,0);
        }
    }
}

extern "C" void kernel_launch(void* const* d_in, const int* in_sizes, int n_in,
                              void* d_out, int out_size, void* d_ws, size_t ws_size,
                              hipStream_t stream) {
    const float* OS    = (const float*)d_in[0];
    const float* IS    = (const float*)d_in[1];
    const float* W_ih0 = (const float*)d_in[2];
    const float* W_hh0 = (const float*)d_in[3];
    const float* b_ih0 = (const float*)d_in[4];
    const float* b_hh0 = (const float*)d_in[5];
    const float* W_ih1 = (const float*)d_in[6];
    const float* W_hh1 = (const float*)d_in[7];
    const float* b_ih1 = (const float*)d_in[8];
    const float* b_hh1 = (const float*)d_in[9];
    float* out = (float*)d_out;
    float* h1  = (float*)d_ws;       // [T, B, 64] f32 = 128 MiB intermediate

    dim3 grid(BATCH, 2), block(64);
    hipLaunchKernelGGL((lstm_rec<0>), grid, block, 0, stream,
                       OS, IS, W_ih0, W_hh0, b_ih0, b_hh0, (const float*)nullptr, h1);
    hipLaunchKernelGGL((lstm_rec<1>), grid, block, 0, stream,
                       (const float*)nullptr, (const float*)nullptr,
                       W_ih1, W_hh1, b_ih1, b_hh1, (const float*)h1, out);
}